// Round 4
// baseline (240.599 us; speedup 1.0000x reference)
//
#include <hip/hip_runtime.h>
#include <stdint.h>
#include <math.h>

typedef float  f32x4  __attribute__((ext_vector_type(4)));
typedef __bf16 bf16x8 __attribute__((ext_vector_type(8)));
typedef __bf16 bf16x4 __attribute__((ext_vector_type(4)));

#define MFMA16(a, b, c) __builtin_amdgcn_mfma_f32_16x16x32_bf16((a), (b), (c), 0, 0, 0)
#define EXP2(x) __builtin_amdgcn_exp2f(x)   // native v_exp_f32

static constexpr int kT = 1024;

// ---- chunk-ordered (MFMA-fragment-ordered) tile layout ----
// 64x64 bf16 tile = 8 chunks x 1024 B; chunk ch, lane l, bf16 j:
//   K^T tile: s = (ch>>1)*16 + (l&15), c = (ch&1)*32 + (l>>4)*8 + j
//   V  tile:  c = (ch>>1)*16 + (l&15), s = (ch&1)*32 + (l>>4)*8 + j
// -> a fragment ds_read_b128 / global b128 is base + lane*16: contiguous,
//    conflict-free, and matches global_load_lds's linear dest.
static constexpr int kTileEl = 4096;                       // 8192 B per tile
static constexpr size_t kTensorEl    = (size_t)128 * 16 * kTileEl;
static constexpr size_t kTensorBytes = kTensorEl * 2;      // 16 MiB per tensor

// legacy constant for fallback kernel
static constexpr int kLS = 72;

__device__ inline void async16(const void* g, void* l) {
  __builtin_amdgcn_global_load_lds(
      (const __attribute__((address_space(1))) void*)g,
      (__attribute__((address_space(3))) void*)l, 16, 0, 0);
}

// ---------------- Prepass: K (mask-folded, transposed) + V, chunk-ordered bf16 ----------------
__global__ __launch_bounds__(256, 8)
void prepass(const float* __restrict__ qkv, const float* __restrict__ mask,
             __bf16* __restrict__ kh, __bf16* __restrict__ vh)
{
  __shared__ float ts[64 * 65];
  const int tid = threadIdx.x;
  const int bid = blockIdx.x, bh = bid >> 4, tile = bid & 15;
  const int b = bh >> 4, h = bh & 15, t0 = tile * 64;
  const float* __restrict__ kb = qkv + (size_t)(b * 3072 + 1024 + h * 64) * kT;
  const float* __restrict__ vb = qkv + (size_t)(b * 3072 + 2048 + h * 64) * kT;
  const float* __restrict__ mrow = mask + (size_t)(h & 7) * kT;  // mask.repeat(n_heads,1)
  const size_t tbase = ((size_t)bh * 16 + tile) * kTileEl;

  // stage K*mask rows into LDS (row c, col s), coalesced f32x4 loads
  const int t4   = (tid & 15) * 4;
  const int crow = tid >> 4;
  const f32x4 m4 = *(const f32x4*)&mrow[t0 + t4];
  #pragma unroll
  for (int i = 0; i < 4; ++i) {
    const int c = i * 16 + crow;
    f32x4 k4 = *(const f32x4*)&kb[(size_t)c * kT + t0 + t4];
    k4 *= m4;                               // fold mask into K (s-axis only dependence)
    *(f32x4*)&ts[c * 65 + t4] = k4;
  }
  __syncthreads();

  // emit 2 pieces/thread: piece p -> chunk p>>6, lane p&63 (writes lane-contiguous)
  #pragma unroll
  for (int i = 0; i < 2; ++i) {
    const int p = i * 256 + tid;
    const int chunk = p >> 6, pl = p & 63;
    // V piece: direct global (16 rows x 128 B contiguous per wave) — issue loads first
    const int vc  = (chunk >> 1) * 16 + (pl & 15);
    const int vs0 = (chunk & 1) * 32 + (pl >> 4) * 8;
    const f32x4 va  = *(const f32x4*)&vb[(size_t)vc * kT + t0 + vs0];
    const f32x4 vbq = *(const f32x4*)&vb[(size_t)vc * kT + t0 + vs0 + 4];
    // K piece from LDS transpose (2-way max bank alias: free for b32)
    const int ks  = (chunk >> 1) * 16 + (pl & 15);
    const int kc0 = (chunk & 1) * 32 + (pl >> 4) * 8;
    bf16x8 k8, v8;
    #pragma unroll
    for (int j = 0; j < 8; ++j) k8[j] = (__bf16)ts[(kc0 + j) * 65 + ks];
    #pragma unroll
    for (int j = 0; j < 4; ++j) { v8[j] = (__bf16)va[j]; v8[4 + j] = (__bf16)vbq[j]; }
    *(bf16x8*)&kh[tbase + (size_t)p * 8] = k8;
    *(bf16x8*)&vh[tbase + (size_t)p * 8] = v8;
  }
}

// ---------------- Main: flash attention, 128-col blocks, 2-tile body, ----------------
// ---------------- 40 KB LDS -> 4 blocks/CU, zero grid tail ----------------
// grid 1024 = 128 bh (low bits -> all 8 t-blocks of one head preserve bid%8 ->
// same XCD -> K/V L2-resident) x 8 t-pairs.  4 blocks/CU x 256 CUs = whole grid
// resident in ONE block-wave (round-3's 49 KB LDS gave 3/CU -> 25% tail tax).
// Per barrier period: TWO K/V tiles (128 s-positions); tile B's 32 QK MFMAs
// cover tile A's exp->ds roundtrip->PV latency chain; 8 barriers total.
// sP is a single 2 KB wave-private buffer reused half0 -> half1 -> next u
// (per-wave DS ops are in program order: reads drain before the next writes).
// No setprio: 4-wave barrier-lockstep structure = the m190 null/negative case.
__global__ __launch_bounds__(256, 4)
void attn_main(const float* __restrict__ qkv,
               const __bf16* __restrict__ kh, const __bf16* __restrict__ vh,
               float* __restrict__ out)
{
  // [0,32768) sK ping-pong 2 x 16 KB (one K-tile PAIR each)
  // [32768,40960) sP: 4 waves x 2048 (shared by both t-halves, sequentially)
  // prologue overlays float ts[64*65] = 16640 B on [0,16640)
  __shared__ __align__(16) char smem[40960];

  const int tid  = threadIdx.x;
  const int lane = tid & 63;
  const int wave = tid >> 6;
  const int quad = lane >> 4;
  const int l15  = lane & 15;

  const int bid = blockIdx.x;
  const int bh  = bid & 127;
  const int tp  = bid >> 7;
  const int b   = bh >> 4;
  const int h   = bh & 15;
  const int t0  = tp * 128;
  const size_t hbase = (size_t)bh * 16;

  // ---- prologue: Q fp32 -> LDS transpose -> hi/lo register frags (both halves) ----
  bf16x8 qh[2][2], ql[2][2];   // [half][kc]
  {
    float* ts = (float*)smem;
    const float* __restrict__ qb = qkv + (size_t)(b * 3072 + h * 64) * kT;
    const int t4   = (tid & 15) * 4;
    const int crow = tid >> 4;
    const int trow = wave * 16 + l15;
    #pragma unroll
    for (int half = 0; half < 2; ++half) {
      const int tq0 = t0 + half * 64;
      #pragma unroll
      for (int i = 0; i < 4; ++i) {
        const int c = i * 16 + crow;
        f32x4 q4 = *(const f32x4*)&qb[(size_t)c * kT + tq0 + t4];
        q4 *= 0.18033688f;                 // 0.125 * log2(e)
        *(f32x4*)&ts[c * 65 + t4] = q4;
      }
      __syncthreads();
      #pragma unroll
      for (int kc = 0; kc < 2; ++kc) {
        bf16x8 hf, lf;
        #pragma unroll
        for (int j = 0; j < 8; ++j) {
          float q = ts[(kc * 32 + quad * 8 + j) * 65 + trow];  // 2-way alias: free
          __bf16 hi = (__bf16)q;
          hf[j] = hi;
          lf[j] = (__bf16)(q - (float)hi);
        }
        qh[half][kc] = hf;
        ql[half][kc] = lf;
      }
      __syncthreads();   // ts free for next half / K DMA below
    }
  }

  // ---- DMA K pair 0 (tiles 0,1 = 16 KB) into buffer 0, distributed across waves ----
  {
    const char* g = (const char*)(kh + hbase * kTileEl) + (size_t)lane * 16;
    for (int i = wave; i < 16; i += 4) async16(g + i * 1024, smem + i * 1024);
  }

  f32x4 O0[4], O1[4];
  #pragma unroll
  for (int cc = 0; cc < 4; ++cc) {
    O0[cc] = (f32x4){0.f, 0.f, 0.f, 0.f};
    O1[cc] = (f32x4){0.f, 0.f, 0.f, 0.f};
  }
  f32x4 la0 = (f32x4){0.f, 0.f, 0.f, 0.f};   // vectorized denominators: 4 indep chains
  f32x4 la1 = (f32x4){0.f, 0.f, 0.f, 0.f};

  char* sPw = smem + 32768 + wave * 2048;   // single wave-private P buffer (2 KB)
  // write addr for (sc): (sc>>1)<<10 | (sc&1)<<9 | pwr   (derived so the 64-lane
  // b64 write covers one contiguous 512 B region; read back is contiguous b128)
  const int pwr = (l15 << 4) + ((quad & 1) << 3) + ((quad >> 1) << 8);

  for (int p = 0; p < 8; ++p) {
    __syncthreads();   // K pair p drained (all waves); other buffer free

    // prefetch K pair p+1 (16 chunks distributed); drains at NEXT barrier
    if (p < 7) {
      const char* g = (const char*)(kh + (hbase + 2 * (p + 1)) * kTileEl) + (size_t)lane * 16;
      char* l = smem + ((p + 1) & 1) * 16384;
      for (int i = wave; i < 16; i += 4) async16(g + i * 1024, l + i * 1024);
    }

    #pragma unroll
    for (int u = 0; u < 2; ++u) {
      const __bf16* __restrict__ vt  = vh + (hbase + 2 * p + u) * kTileEl;
      const __bf16* __restrict__ sKt = (const __bf16*)(smem + (p & 1) * 16384 + u * 8192);

      // V frags kc=0: coalesced 1 KB b128 loads, issued early
      bf16x8 vf0[4], vf1[4];
      #pragma unroll
      for (int cc = 0; cc < 4; ++cc)
        vf0[cc] = *(const bf16x8*)&vt[(size_t)(cc * 2) * 512 + lane * 8];

      // ---- QK (2-term hi/lo), two independent chains per sc + exp2 ----
      // half-0 P staged to LDS now; half-1 P parked in registers (8 VGPR)
      bf16x4 p1s[4];
      #pragma unroll
      for (int sc = 0; sc < 4; ++sc) {
        bf16x8 k0 = *(const bf16x8*)&sKt[(size_t)(sc * 2) * 512 + lane * 8];
        bf16x8 k1 = *(const bf16x8*)&sKt[(size_t)(sc * 2 + 1) * 512 + lane * 8];
        f32x4 a0 = (f32x4){0.f, 0.f, 0.f, 0.f};
        f32x4 a1 = (f32x4){0.f, 0.f, 0.f, 0.f};
        a0 = MFMA16(k0, ql[0][0], a0);
        a1 = MFMA16(k0, ql[1][0], a1);
        a0 = MFMA16(k0, qh[0][0], a0);
        a1 = MFMA16(k0, qh[1][0], a1);
        a0 = MFMA16(k1, ql[0][1], a0);
        a1 = MFMA16(k1, ql[1][1], a1);
        a0 = MFMA16(k1, qh[0][1], a0);
        a1 = MFMA16(k1, qh[1][1], a1);
        f32x4 e0, e1;
        #pragma unroll
        for (int r = 0; r < 4; ++r) {
          e0[r] = EXP2(a0[r]);
          e1[r] = EXP2(a1[r]);
        }
        la0 += e0;                        // f32 denominator, 4 indep chains
        la1 += e1;
        bf16x4 p0;
        #pragma unroll
        for (int r = 0; r < 4; ++r) {
          p0[r] = (__bf16)e0[r];
          p1s[sc][r] = (__bf16)e1[r];
        }
        *(bf16x4*)(sPw + (((sc >> 1) << 10) + ((sc & 1) << 9) + pwr)) = p0;
      }

      // V frags kc=1
      #pragma unroll
      for (int cc = 0; cc < 4; ++cc)
        vf1[cc] = *(const bf16x8*)&vt[(size_t)(cc * 2 + 1) * 512 + lane * 8];

      // half-0 P frags: contiguous 1 KB b128 reads (in-wave DS ordering)
      bf16x8 pb00 = *(const bf16x8*)(sPw + lane * 16);
      bf16x8 pb01 = *(const bf16x8*)(sPw + 1024 + lane * 16);

      #pragma unroll
      for (int cc = 0; cc < 4; ++cc) {
        O0[cc] = MFMA16(vf0[cc], pb00, O0[cc]);
        O0[cc] = MFMA16(vf1[cc], pb01, O0[cc]);
      }

      // half-1 P through the SAME buffer (in-wave DS ordering: reads above
      // complete before these writes land; no barrier needed)
      #pragma unroll
      for (int sc = 0; sc < 4; ++sc)
        *(bf16x4*)(sPw + (((sc >> 1) << 10) + ((sc & 1) << 9) + pwr)) = p1s[sc];

      bf16x8 pb10 = *(const bf16x8*)(sPw + lane * 16);
      bf16x8 pb11 = *(const bf16x8*)(sPw + 1024 + lane * 16);

      #pragma unroll
      for (int cc = 0; cc < 4; ++cc) {
        O1[cc] = MFMA16(vf0[cc], pb10, O1[cc]);
        O1[cc] = MFMA16(vf1[cc], pb11, O1[cc]);
      }
    }
  }

  // ---- epilogue: reduce denominators (4 lanes of f32x4, then cross-quad), store ----
  float ls0 = la0[0] + la0[1] + la0[2] + la0[3];
  float ls1 = la1[0] + la1[1] + la1[2] + la1[3];
  ls0 += __shfl_xor(ls0, 16);
  ls0 += __shfl_xor(ls0, 32);
  ls1 += __shfl_xor(ls1, 16);
  ls1 += __shfl_xor(ls1, 32);
  const float inv0 = 1.0f / ls0;
  const float inv1 = 1.0f / ls1;

  const int tcol = t0 + wave * 16 + l15;
  float* __restrict__ obase = out + (size_t)b * (1024 * 1024) + (size_t)(h * 64) * kT;
  #pragma unroll
  for (int cc = 0; cc < 4; ++cc) {
    #pragma unroll
    for (int r = 0; r < 4; ++r) {
      const int c = cc * 16 + quad * 4 + r;
      obase[(size_t)c * kT + tcol]      = O0[cc][r] * inv0;
      obase[(size_t)c * kT + tcol + 64] = O1[cc][r] * inv1;
    }
  }
}

// ---------------- Fallback (round-2 passing kernel, used if ws too small) ----------------
__global__ __launch_bounds__(256, 2)
void attn_fused(const float* __restrict__ qkv, const float* __restrict__ mask,
                float* __restrict__ out)
{
  __shared__ __align__(16) __bf16 Ahi[64 * kLS];
  __shared__ __align__(16) __bf16 Alo[64 * kLS];
  __shared__ __align__(16) __bf16 Vhi[64 * kLS];
  __shared__ __align__(16) __bf16 Vlo[64 * kLS];
  __shared__ __align__(16) __bf16 Phi[64 * kLS];
  __shared__ __align__(16) __bf16 Plo[64 * kLS];
  __shared__ __align__(16) float  ms[64];

  const int tid  = threadIdx.x;
  const int lane = tid & 63;
  const int wave = tid >> 6;
  const int quad = lane >> 4;
  const int l15  = lane & 15;

  const int bid = blockIdx.x;
  const int bh  = bid >> 4;
  const int tb  = bid & 15;
  const int b   = bh >> 4;
  const int h   = bh & 15;
  const int t0  = tb * 64;

  const float* __restrict__ qbase = qkv + (size_t)(b * 3072 + h * 64) * kT;
  const float* __restrict__ kbase = qkv + (size_t)(b * 3072 + 1024 + h * 64) * kT;
  const float* __restrict__ vbase = qkv + (size_t)(b * 3072 + 2048 + h * 64) * kT;
  const float* __restrict__ mrow  = mask + (size_t)(h & 7) * kT;

  const int sl = tid & 63;
  const int cg = tid >> 6;

  #pragma unroll
  for (int i = 0; i < 16; ++i) {
    const int c = cg * 16 + i;
    float v  = qbase[(size_t)c * kT + t0 + sl] * 0.125f;
    __bf16 hi = (__bf16)v;
    Ahi[sl * kLS + c] = hi;
    Alo[sl * kLS + c] = (__bf16)(v - (float)hi);
  }
  __syncthreads();

  bf16x8 qh[2], ql[2];
  {
    const int row = (wave * 16 + l15) * kLS;
    #pragma unroll
    for (int kc = 0; kc < 2; ++kc) {
      qh[kc] = *(const bf16x8*)&Ahi[row + kc * 32 + quad * 8];
      ql[kc] = *(const bf16x8*)&Alo[row + kc * 32 + quad * 8];
    }
  }
  __syncthreads();

  f32x4 O[4];
  #pragma unroll
  for (int cc = 0; cc < 4; ++cc) O[cc] = (f32x4){0.f, 0.f, 0.f, 0.f};
  float m_run = -__builtin_inff();
  float l_run = 0.f;

  for (int s0 = 0; s0 < kT; s0 += 64) {
    #pragma unroll
    for (int i = 0; i < 16; ++i) {
      const int c = cg * 16 + i;
      float kv   = kbase[(size_t)c * kT + s0 + sl];
      __bf16 khi = (__bf16)kv;
      Ahi[sl * kLS + c] = khi;
      Alo[sl * kLS + c] = (__bf16)(kv - (float)khi);
      float vv   = vbase[(size_t)c * kT + s0 + sl];
      __bf16 vhi = (__bf16)vv;
      Vhi[c * kLS + sl] = vhi;
      Vlo[c * kLS + sl] = (__bf16)(vv - (float)vhi);
    }
    if (tid < 64) ms[tid] = mrow[s0 + tid];
    __syncthreads();

    f32x4 S[4];
    #pragma unroll
    for (int sc = 0; sc < 4; ++sc) {
      f32x4 acc = (f32x4){0.f, 0.f, 0.f, 0.f};
      #pragma unroll
      for (int kc = 0; kc < 2; ++kc) {
        const int off = (sc * 16 + l15) * kLS + kc * 32 + quad * 8;
        bf16x8 kh8 = *(const bf16x8*)&Ahi[off];
        bf16x8 kl8 = *(const bf16x8*)&Alo[off];
        acc = MFMA16(kh8, ql[kc], acc);
        acc = MFMA16(kl8, qh[kc], acc);
        acc = MFMA16(kh8, qh[kc], acc);
      }
      S[sc] = acc;
    }

    float x[16];
    float tmax = -__builtin_inff();
    #pragma unroll
    for (int sc = 0; sc < 4; ++sc) {
      f32x4 mv = *(const f32x4*)&ms[sc * 16 + quad * 4];
      #pragma unroll
      for (int r = 0; r < 4; ++r) {
        float xv = S[sc][r] * mv[r];
        x[sc * 4 + r] = xv;
        tmax = fmaxf(tmax, xv);
      }
    }
    tmax = fmaxf(tmax, __shfl_xor(tmax, 16));
    tmax = fmaxf(tmax, __shfl_xor(tmax, 32));
    const float mnew  = fmaxf(m_run, tmax);
    const float alpha = __expf(m_run - mnew);
    float tsum = 0.f;
    #pragma unroll
    for (int i = 0; i < 16; ++i) {
      float p = __expf(x[i] - mnew);
      x[i] = p;
      tsum += p;
    }
    tsum += __shfl_xor(tsum, 16);
    tsum += __shfl_xor(tsum, 32);
    l_run = l_run * alpha + tsum;
    m_run = mnew;
    #pragma unroll
    for (int cc = 0; cc < 4; ++cc) O[cc] = O[cc] * alpha;

    const int prow = (wave * 16 + l15) * kLS;
    #pragma unroll
    for (int sc = 0; sc < 4; ++sc) {
      bf16x4 ph, pl;
      #pragma unroll
      for (int r = 0; r < 4; ++r) {
        float p   = x[sc * 4 + r];
        __bf16 hi = (__bf16)p;
        ph[r] = hi;
        pl[r] = (__bf16)(p - (float)hi);
      }
      *(bf16x4*)&Phi[prow + sc * 16 + quad * 4] = ph;
      *(bf16x4*)&Plo[prow + sc * 16 + quad * 4] = pl;
    }
    __syncthreads();

    bf16x8 pbh[2], pbl[2];
    #pragma unroll
    for (int kc = 0; kc < 2; ++kc) {
      pbh[kc] = *(const bf16x8*)&Phi[prow + kc * 32 + quad * 8];
      pbl[kc] = *(const bf16x8*)&Plo[prow + kc * 32 + quad * 8];
    }
    #pragma unroll
    for (int cc = 0; cc < 4; ++cc) {
      #pragma unroll
      for (int kc = 0; kc < 2; ++kc) {
        const int off = (cc * 16 + l15) * kLS + kc * 32 + quad * 8;
        bf16x8 v8 = *(const bf16x8*)&Vhi[off];
        bf16x8 w8 = *(const bf16x8*)&Vlo[off];
        O[cc] = MFMA16(v8, pbl[kc], O[cc]);
        O[cc] = MFMA16(w8, pbh[kc], O[cc]);
        O[cc] = MFMA16(v8, pbh[kc], O[cc]);
      }
    }
    __syncthreads();
  }

  const float inv  = 1.0f / l_run;
  const int   tcol = t0 + wave * 16 + l15;
  float* __restrict__ obase = out + (size_t)b * (1024 * 1024) + (size_t)(h * 64) * kT;
  #pragma unroll
  for (int cc = 0; cc < 4; ++cc) {
    #pragma unroll
    for (int r = 0; r < 4; ++r) {
      const int c = cc * 16 + quad * 4 + r;
      obase[(size_t)c * kT + tcol] = O[cc][r] * inv;
    }
  }
}

extern "C" void kernel_launch(void* const* d_in, const int* in_sizes, int n_in,
                              void* d_out, int out_size, void* d_ws, size_t ws_size,
                              hipStream_t stream)
{
  const float* qkv  = (const float*)d_in[0];  // (8, 3072, 1024) fp32
  const float* mask = (const float*)d_in[1];  // (8, 1024) fp32
  float* out = (float*)d_out;                 // (8, 1024, 1024) fp32
  (void)in_sizes; (void)n_in; (void)out_size;

  if (ws_size >= 2 * kTensorBytes) {
    char* w = (char*)d_ws;
    __bf16* kh = (__bf16*)(w + 0 * kTensorBytes);
    __bf16* vh = (__bf16*)(w + 1 * kTensorBytes);
    prepass<<<dim3(2048), dim3(256), 0, stream>>>(qkv, mask, kh, vh);
    attn_main<<<dim3(1024), dim3(256), 0, stream>>>(qkv, kh, vh, out);
  } else {
    attn_fused<<<dim3(2048), dim3(256), 0, stream>>>(qkv, mask, out);
  }
}

// Round 5
// 211.656 us; speedup vs baseline: 1.1367x; 1.1367x over previous
//
#include <hip/hip_runtime.h>
#include <stdint.h>
#include <math.h>

typedef float  f32x4  __attribute__((ext_vector_type(4)));
typedef __bf16 bf16x8 __attribute__((ext_vector_type(8)));
typedef __bf16 bf16x4 __attribute__((ext_vector_type(4)));

#define MFMA16(a, b, c) __builtin_amdgcn_mfma_f32_16x16x32_bf16((a), (b), (c), 0, 0, 0)
#define EXP2(x) __builtin_amdgcn_exp2f(x)   // native v_exp_f32

static constexpr int kT = 1024;

// ---- chunk-ordered (MFMA-fragment-ordered) tile layout ----
// 64x64 bf16 tile = 8 chunks x 1024 B; chunk ch, lane l, bf16 j:
//   K^T tile: s = (ch>>1)*16 + (l&15), c = (ch&1)*32 + (l>>4)*8 + j
//   V  tile:  c = (ch>>1)*16 + (l&15), s = (ch&1)*32 + (l>>4)*8 + j
// -> a fragment ds_read_b128 / global b128 is base + lane*16: contiguous,
//    conflict-free, and matches global_load_lds's linear dest.
static constexpr int kTileEl = 4096;                       // 8192 B per tile
static constexpr size_t kTensorEl    = (size_t)128 * 16 * kTileEl;
static constexpr size_t kTensorBytes = kTensorEl * 2;      // 16 MiB per tensor

// legacy constant for fallback kernel
static constexpr int kLS = 72;

__device__ inline void async16(const void* g, void* l) {
  __builtin_amdgcn_global_load_lds(
      (const __attribute__((address_space(1))) void*)g,
      (__attribute__((address_space(3))) void*)l, 16, 0, 0);
}

// ---------------- Prepass: K (mask-folded, transposed) + V, chunk-ordered bf16 ----------------
__global__ __launch_bounds__(256, 8)
void prepass(const float* __restrict__ qkv, const float* __restrict__ mask,
             __bf16* __restrict__ kh, __bf16* __restrict__ vh)
{
  __shared__ float ts[64 * 65];
  const int tid = threadIdx.x;
  const int bid = blockIdx.x, bh = bid >> 4, tile = bid & 15;
  const int b = bh >> 4, h = bh & 15, t0 = tile * 64;
  const float* __restrict__ kb = qkv + (size_t)(b * 3072 + 1024 + h * 64) * kT;
  const float* __restrict__ vb = qkv + (size_t)(b * 3072 + 2048 + h * 64) * kT;
  const float* __restrict__ mrow = mask + (size_t)(h & 7) * kT;  // mask.repeat(n_heads,1)
  const size_t tbase = ((size_t)bh * 16 + tile) * kTileEl;

  // stage K*mask rows into LDS (row c, col s), coalesced f32x4 loads
  const int t4   = (tid & 15) * 4;
  const int crow = tid >> 4;
  const f32x4 m4 = *(const f32x4*)&mrow[t0 + t4];
  #pragma unroll
  for (int i = 0; i < 4; ++i) {
    const int c = i * 16 + crow;
    f32x4 k4 = *(const f32x4*)&kb[(size_t)c * kT + t0 + t4];
    k4 *= m4;                               // fold mask into K (s-axis only dependence)
    *(f32x4*)&ts[c * 65 + t4] = k4;
  }
  __syncthreads();

  // emit 2 pieces/thread: piece p -> chunk p>>6, lane p&63 (writes lane-contiguous)
  #pragma unroll
  for (int i = 0; i < 2; ++i) {
    const int p = i * 256 + tid;
    const int chunk = p >> 6, pl = p & 63;
    // V piece: direct global (16 rows x 128 B contiguous per wave) — issue loads first
    const int vc  = (chunk >> 1) * 16 + (pl & 15);
    const int vs0 = (chunk & 1) * 32 + (pl >> 4) * 8;
    const f32x4 va  = *(const f32x4*)&vb[(size_t)vc * kT + t0 + vs0];
    const f32x4 vbq = *(const f32x4*)&vb[(size_t)vc * kT + t0 + vs0 + 4];
    // K piece from LDS transpose (2-way max bank alias: free for b32)
    const int ks  = (chunk >> 1) * 16 + (pl & 15);
    const int kc0 = (chunk & 1) * 32 + (pl >> 4) * 8;
    bf16x8 k8, v8;
    #pragma unroll
    for (int j = 0; j < 8; ++j) k8[j] = (__bf16)ts[(kc0 + j) * 65 + ks];
    #pragma unroll
    for (int j = 0; j < 4; ++j) { v8[j] = (__bf16)va[j]; v8[4 + j] = (__bf16)vbq[j]; }
    *(bf16x8*)&kh[tbase + (size_t)p * 8] = k8;
    *(bf16x8*)&vh[tbase + (size_t)p * 8] = v8;
  }
}

// ---------------- Main: flash attention, 128-col blocks, 2-tile body, ----------------
// ---------------- sequential halves (no register parking -> no spill) ----------------
// grid 1024 = 128 bh (low bits -> all 8 t-blocks of one head preserve bid%8 ->
// same XCD -> K/V L2-resident) x 8 t-pairs.  40 KB LDS -> 4 blocks/CU: whole
// grid resident in ONE block-wave (no tail).
// Per barrier period: TWO K/V tiles; 8 barriers total.
// Each u: QK half-0 -> sP -> PV half-0 -> QK half-1 -> sP -> PV half-1.
// The single 2 KB wave-private sP is reused 4x per pair; per-wave DS program
// order guarantees reads drain before the next writes land (no barrier).
// ROUND-4 LESSON: parking half-1 P in registers across PV half-0 pushed the
// unified VGPR+AGPR budget past the 128 cap of __launch_bounds__(256,4) ->
// per-iteration scratch spill (+158 MB HBM writes, 107 us). Sequential halves
// keep peak live regs ~30 lower; half-1 QK is still independent work the
// scheduler overlaps with half-0 PV.
__global__ __launch_bounds__(256, 4)
void attn_main(const float* __restrict__ qkv,
               const __bf16* __restrict__ kh, const __bf16* __restrict__ vh,
               float* __restrict__ out)
{
  // [0,32768) sK ping-pong 2 x 16 KB (one K-tile PAIR each)
  // [32768,40960) sP: 4 waves x 2048 (shared by both t-halves, sequentially)
  // prologue overlays float ts[64*65] = 16640 B on [0,16640)
  __shared__ __align__(16) char smem[40960];

  const int tid  = threadIdx.x;
  const int lane = tid & 63;
  const int wave = tid >> 6;
  const int quad = lane >> 4;
  const int l15  = lane & 15;

  const int bid = blockIdx.x;
  const int bh  = bid & 127;
  const int tp  = bid >> 7;
  const int b   = bh >> 4;
  const int h   = bh & 15;
  const int t0  = tp * 128;
  const size_t hbase = (size_t)bh * 16;

  // ---- prologue: Q fp32 -> LDS transpose -> hi/lo register frags (both halves) ----
  bf16x8 qh[2][2], ql[2][2];   // [half][kc]
  {
    float* ts = (float*)smem;
    const float* __restrict__ qb = qkv + (size_t)(b * 3072 + h * 64) * kT;
    const int t4   = (tid & 15) * 4;
    const int crow = tid >> 4;
    const int trow = wave * 16 + l15;
    #pragma unroll
    for (int half = 0; half < 2; ++half) {
      const int tq0 = t0 + half * 64;
      #pragma unroll
      for (int i = 0; i < 4; ++i) {
        const int c = i * 16 + crow;
        f32x4 q4 = *(const f32x4*)&qb[(size_t)c * kT + tq0 + t4];
        q4 *= 0.18033688f;                 // 0.125 * log2(e)
        *(f32x4*)&ts[c * 65 + t4] = q4;
      }
      __syncthreads();
      #pragma unroll
      for (int kc = 0; kc < 2; ++kc) {
        bf16x8 hf, lf;
        #pragma unroll
        for (int j = 0; j < 8; ++j) {
          float q = ts[(kc * 32 + quad * 8 + j) * 65 + trow];  // 2-way alias: free
          __bf16 hi = (__bf16)q;
          hf[j] = hi;
          lf[j] = (__bf16)(q - (float)hi);
        }
        qh[half][kc] = hf;
        ql[half][kc] = lf;
      }
      __syncthreads();   // ts free for next half / K DMA below
    }
  }

  // ---- DMA K pair 0 (tiles 0,1 = 16 KB) into buffer 0, distributed across waves ----
  {
    const char* g = (const char*)(kh + hbase * kTileEl) + (size_t)lane * 16;
    for (int i = wave; i < 16; i += 4) async16(g + i * 1024, smem + i * 1024);
  }

  f32x4 O0[4], O1[4];
  #pragma unroll
  for (int cc = 0; cc < 4; ++cc) {
    O0[cc] = (f32x4){0.f, 0.f, 0.f, 0.f};
    O1[cc] = (f32x4){0.f, 0.f, 0.f, 0.f};
  }
  f32x4 la0 = (f32x4){0.f, 0.f, 0.f, 0.f};   // vectorized denominators: 4 indep chains
  f32x4 la1 = (f32x4){0.f, 0.f, 0.f, 0.f};

  char* sPw = smem + 32768 + wave * 2048;   // single wave-private P buffer (2 KB)
  // write addr for (sc): (sc>>1)<<10 | (sc&1)<<9 | pwr   (derived so the 64-lane
  // b64 write covers one contiguous 512 B region; read back is contiguous b128)
  const int pwr = (l15 << 4) + ((quad & 1) << 3) + ((quad >> 1) << 8);

  for (int p = 0; p < 8; ++p) {
    __syncthreads();   // K pair p drained (all waves); other buffer free

    // prefetch K pair p+1 (16 chunks distributed); drains at NEXT barrier
    if (p < 7) {
      const char* g = (const char*)(kh + (hbase + 2 * (p + 1)) * kTileEl) + (size_t)lane * 16;
      char* l = smem + ((p + 1) & 1) * 16384;
      for (int i = wave; i < 16; i += 4) async16(g + i * 1024, l + i * 1024);
    }

    #pragma unroll
    for (int u = 0; u < 2; ++u) {
      const __bf16* __restrict__ vt  = vh + (hbase + 2 * p + u) * kTileEl;
      const __bf16* __restrict__ sKt = (const __bf16*)(smem + (p & 1) * 16384 + u * 8192);

      // V frags: coalesced 1 KB b128 loads, issued early (cover QK latency)
      bf16x8 vf0[4], vf1[4];
      #pragma unroll
      for (int cc = 0; cc < 4; ++cc)
        vf0[cc] = *(const bf16x8*)&vt[(size_t)(cc * 2) * 512 + lane * 8];

      // ---- QK half-0 (2-term hi/lo) + exp2 -> sP ----
      #pragma unroll
      for (int sc = 0; sc < 4; ++sc) {
        bf16x8 k0 = *(const bf16x8*)&sKt[(size_t)(sc * 2) * 512 + lane * 8];
        bf16x8 k1 = *(const bf16x8*)&sKt[(size_t)(sc * 2 + 1) * 512 + lane * 8];
        f32x4 a0 = (f32x4){0.f, 0.f, 0.f, 0.f};
        a0 = MFMA16(k0, ql[0][0], a0);
        a0 = MFMA16(k0, qh[0][0], a0);
        a0 = MFMA16(k1, ql[0][1], a0);
        a0 = MFMA16(k1, qh[0][1], a0);
        f32x4 e0;
        #pragma unroll
        for (int r = 0; r < 4; ++r) e0[r] = EXP2(a0[r]);
        la0 += e0;                        // f32 denominator, 4 indep chains
        bf16x4 p0;
        #pragma unroll
        for (int r = 0; r < 4; ++r) p0[r] = (__bf16)e0[r];
        *(bf16x4*)(sPw + (((sc >> 1) << 10) + ((sc & 1) << 9) + pwr)) = p0;
      }

      #pragma unroll
      for (int cc = 0; cc < 4; ++cc)
        vf1[cc] = *(const bf16x8*)&vt[(size_t)(cc * 2 + 1) * 512 + lane * 8];

      // half-0 P frags: contiguous 1 KB b128 reads (in-wave DS ordering)
      bf16x8 pb00 = *(const bf16x8*)(sPw + lane * 16);
      bf16x8 pb01 = *(const bf16x8*)(sPw + 1024 + lane * 16);

      // ---- PV half-0 (independent of QK half-1 below: scheduler overlaps) ----
      #pragma unroll
      for (int cc = 0; cc < 4; ++cc) {
        O0[cc] = MFMA16(vf0[cc], pb00, O0[cc]);
        O0[cc] = MFMA16(vf1[cc], pb01, O0[cc]);
      }

      // ---- QK half-1 through the SAME sP (program-order safe: pb0 reads
      // above complete before these writes land) ----
      #pragma unroll
      for (int sc = 0; sc < 4; ++sc) {
        bf16x8 k0 = *(const bf16x8*)&sKt[(size_t)(sc * 2) * 512 + lane * 8];
        bf16x8 k1 = *(const bf16x8*)&sKt[(size_t)(sc * 2 + 1) * 512 + lane * 8];
        f32x4 a1 = (f32x4){0.f, 0.f, 0.f, 0.f};
        a1 = MFMA16(k0, ql[1][0], a1);
        a1 = MFMA16(k0, qh[1][0], a1);
        a1 = MFMA16(k1, ql[1][1], a1);
        a1 = MFMA16(k1, qh[1][1], a1);
        f32x4 e1;
        #pragma unroll
        for (int r = 0; r < 4; ++r) e1[r] = EXP2(a1[r]);
        la1 += e1;
        bf16x4 p1;
        #pragma unroll
        for (int r = 0; r < 4; ++r) p1[r] = (__bf16)e1[r];
        *(bf16x4*)(sPw + (((sc >> 1) << 10) + ((sc & 1) << 9) + pwr)) = p1;
      }

      bf16x8 pb10 = *(const bf16x8*)(sPw + lane * 16);
      bf16x8 pb11 = *(const bf16x8*)(sPw + 1024 + lane * 16);

      // ---- PV half-1 ----
      #pragma unroll
      for (int cc = 0; cc < 4; ++cc) {
        O1[cc] = MFMA16(vf0[cc], pb10, O1[cc]);
        O1[cc] = MFMA16(vf1[cc], pb11, O1[cc]);
      }
    }
  }

  // ---- epilogue: reduce denominators (4 lanes of f32x4, then cross-quad), store ----
  float ls0 = la0[0] + la0[1] + la0[2] + la0[3];
  float ls1 = la1[0] + la1[1] + la1[2] + la1[3];
  ls0 += __shfl_xor(ls0, 16);
  ls0 += __shfl_xor(ls0, 32);
  ls1 += __shfl_xor(ls1, 16);
  ls1 += __shfl_xor(ls1, 32);
  const float inv0 = 1.0f / ls0;
  const float inv1 = 1.0f / ls1;

  const int tcol = t0 + wave * 16 + l15;
  float* __restrict__ obase = out + (size_t)b * (1024 * 1024) + (size_t)(h * 64) * kT;
  #pragma unroll
  for (int cc = 0; cc < 4; ++cc) {
    #pragma unroll
    for (int r = 0; r < 4; ++r) {
      const int c = cc * 16 + quad * 4 + r;
      obase[(size_t)c * kT + tcol]      = O0[cc][r] * inv0;
      obase[(size_t)c * kT + tcol + 64] = O1[cc][r] * inv1;
    }
  }
}

// ---------------- Fallback (round-2 passing kernel, used if ws too small) ----------------
__global__ __launch_bounds__(256, 2)
void attn_fused(const float* __restrict__ qkv, const float* __restrict__ mask,
                float* __restrict__ out)
{
  __shared__ __align__(16) __bf16 Ahi[64 * kLS];
  __shared__ __align__(16) __bf16 Alo[64 * kLS];
  __shared__ __align__(16) __bf16 Vhi[64 * kLS];
  __shared__ __align__(16) __bf16 Vlo[64 * kLS];
  __shared__ __align__(16) __bf16 Phi[64 * kLS];
  __shared__ __align__(16) __bf16 Plo[64 * kLS];
  __shared__ __align__(16) float  ms[64];

  const int tid  = threadIdx.x;
  const int lane = tid & 63;
  const int wave = tid >> 6;
  const int quad = lane >> 4;
  const int l15  = lane & 15;

  const int bid = blockIdx.x;
  const int bh  = bid >> 4;
  const int tb  = bid & 15;
  const int b   = bh >> 4;
  const int h   = bh & 15;
  const int t0  = tb * 64;

  const float* __restrict__ qbase = qkv + (size_t)(b * 3072 + h * 64) * kT;
  const float* __restrict__ kbase = qkv + (size_t)(b * 3072 + 1024 + h * 64) * kT;
  const float* __restrict__ vbase = qkv + (size_t)(b * 3072 + 2048 + h * 64) * kT;
  const float* __restrict__ mrow  = mask + (size_t)(h & 7) * kT;

  const int sl = tid & 63;
  const int cg = tid >> 6;

  #pragma unroll
  for (int i = 0; i < 16; ++i) {
    const int c = cg * 16 + i;
    float v  = qbase[(size_t)c * kT + t0 + sl] * 0.125f;
    __bf16 hi = (__bf16)v;
    Ahi[sl * kLS + c] = hi;
    Alo[sl * kLS + c] = (__bf16)(v - (float)hi);
  }
  __syncthreads();

  bf16x8 qh[2], ql[2];
  {
    const int row = (wave * 16 + l15) * kLS;
    #pragma unroll
    for (int kc = 0; kc < 2; ++kc) {
      qh[kc] = *(const bf16x8*)&Ahi[row + kc * 32 + quad * 8];
      ql[kc] = *(const bf16x8*)&Alo[row + kc * 32 + quad * 8];
    }
  }
  __syncthreads();

  f32x4 O[4];
  #pragma unroll
  for (int cc = 0; cc < 4; ++cc) O[cc] = (f32x4){0.f, 0.f, 0.f, 0.f};
  float m_run = -__builtin_inff();
  float l_run = 0.f;

  for (int s0 = 0; s0 < kT; s0 += 64) {
    #pragma unroll
    for (int i = 0; i < 16; ++i) {
      const int c = cg * 16 + i;
      float kv   = kbase[(size_t)c * kT + s0 + sl];
      __bf16 khi = (__bf16)kv;
      Ahi[sl * kLS + c] = khi;
      Alo[sl * kLS + c] = (__bf16)(kv - (float)khi);
      float vv   = vbase[(size_t)c * kT + s0 + sl];
      __bf16 vhi = (__bf16)vv;
      Vhi[c * kLS + sl] = vhi;
      Vlo[c * kLS + sl] = (__bf16)(vv - (float)vhi);
    }
    if (tid < 64) ms[tid] = mrow[s0 + tid];
    __syncthreads();

    f32x4 S[4];
    #pragma unroll
    for (int sc = 0; sc < 4; ++sc) {
      f32x4 acc = (f32x4){0.f, 0.f, 0.f, 0.f};
      #pragma unroll
      for (int kc = 0; kc < 2; ++kc) {
        const int off = (sc * 16 + l15) * kLS + kc * 32 + quad * 8;
        bf16x8 kh8 = *(const bf16x8*)&Ahi[off];
        bf16x8 kl8 = *(const bf16x8*)&Alo[off];
        acc = MFMA16(kh8, ql[kc], acc);
        acc = MFMA16(kl8, qh[kc], acc);
        acc = MFMA16(kh8, qh[kc], acc);
      }
      S[sc] = acc;
    }

    float x[16];
    float tmax = -__builtin_inff();
    #pragma unroll
    for (int sc = 0; sc < 4; ++sc) {
      f32x4 mv = *(const f32x4*)&ms[sc * 16 + quad * 4];
      #pragma unroll
      for (int r = 0; r < 4; ++r) {
        float xv = S[sc][r] * mv[r];
        x[sc * 4 + r] = xv;
        tmax = fmaxf(tmax, xv);
      }
    }
    tmax = fmaxf(tmax, __shfl_xor(tmax, 16));
    tmax = fmaxf(tmax, __shfl_xor(tmax, 32));
    const float mnew  = fmaxf(m_run, tmax);
    const float alpha = __expf(m_run - mnew);
    float tsum = 0.f;
    #pragma unroll
    for (int i = 0; i < 16; ++i) {
      float p = __expf(x[i] - mnew);
      x[i] = p;
      tsum += p;
    }
    tsum += __shfl_xor(tsum, 16);
    tsum += __shfl_xor(tsum, 32);
    l_run = l_run * alpha + tsum;
    m_run = mnew;
    #pragma unroll
    for (int cc = 0; cc < 4; ++cc) O[cc] = O[cc] * alpha;

    const int prow = (wave * 16 + l15) * kLS;
    #pragma unroll
    for (int sc = 0; sc < 4; ++sc) {
      bf16x4 ph, pl;
      #pragma unroll
      for (int r = 0; r < 4; ++r) {
        float p   = x[sc * 4 + r];
        __bf16 hi = (__bf16)p;
        ph[r] = hi;
        pl[r] = (__bf16)(p - (float)hi);
      }
      *(bf16x4*)&Phi[prow + sc * 16 + quad * 4] = ph;
      *(bf16x4*)&Plo[prow + sc * 16 + quad * 4] = pl;
    }
    __syncthreads();

    bf16x8 pbh[2], pbl[2];
    #pragma unroll
    for (int kc = 0; kc < 2; ++kc) {
      pbh[kc] = *(const bf16x8*)&Phi[prow + kc * 32 + quad * 8];
      pbl[kc] = *(const bf16x8*)&Plo[prow + kc * 32 + quad * 8];
    }
    #pragma unroll
    for (int cc = 0; cc < 4; ++cc) {
      #pragma unroll
      for (int kc = 0; kc < 2; ++kc) {
        const int off = (cc * 16 + l15) * kLS + kc * 32 + quad * 8;
        bf16x8 v8 = *(const bf16x8*)&Vhi[off];
        bf16x8 w8 = *(const bf16x8*)&Vlo[off];
        O[cc] = MFMA16(v8, pbl[kc], O[cc]);
        O[cc] = MFMA16(w8, pbh[kc], O[cc]);
        O[cc] = MFMA16(v8, pbh[kc], O[cc]);
      }
    }
    __syncthreads();
  }

  const float inv  = 1.0f / l_run;
  const int   tcol = t0 + wave * 16 + l15;
  float* __restrict__ obase = out + (size_t)b * (1024 * 1024) + (size_t)(h * 64) * kT;
  #pragma unroll
  for (int cc = 0; cc < 4; ++cc) {
    #pragma unroll
    for (int r = 0; r < 4; ++r) {
      const int c = cc * 16 + quad * 4 + r;
      obase[(size_t)c * kT + tcol] = O[cc][r] * inv;
    }
  }
}

extern "C" void kernel_launch(void* const* d_in, const int* in_sizes, int n_in,
                              void* d_out, int out_size, void* d_ws, size_t ws_size,
                              hipStream_t stream)
{
  const float* qkv  = (const float*)d_in[0];  // (8, 3072, 1024) fp32
  const float* mask = (const float*)d_in[1];  // (8, 1024) fp32
  float* out = (float*)d_out;                 // (8, 1024, 1024) fp32
  (void)in_sizes; (void)n_in; (void)out_size;

  if (ws_size >= 2 * kTensorBytes) {
    char* w = (char*)d_ws;
    __bf16* kh = (__bf16*)(w + 0 * kTensorBytes);
    __bf16* vh = (__bf16*)(w + 1 * kTensorBytes);
    prepass<<<dim3(2048), dim3(256), 0, stream>>>(qkv, mask, kh, vh);
    attn_main<<<dim3(1024), dim3(256), 0, stream>>>(qkv, kh, vh, out);
  } else {
    attn_fused<<<dim3(2048), dim3(256), 0, stream>>>(qkv, mask, out);
  }
}

// Round 7
// 202.596 us; speedup vs baseline: 1.1876x; 1.0447x over previous
//
#include <hip/hip_runtime.h>
#include <stdint.h>
#include <math.h>

typedef float  f32x4  __attribute__((ext_vector_type(4)));
typedef __bf16 bf16x8 __attribute__((ext_vector_type(8)));
typedef __bf16 bf16x4 __attribute__((ext_vector_type(4)));

#define MFMA16(a, b, c) __builtin_amdgcn_mfma_f32_16x16x32_bf16((a), (b), (c), 0, 0, 0)
#define EXP2(x) __builtin_amdgcn_exp2f(x)   // native v_exp_f32

static constexpr int kT = 1024;

// ---- chunk-ordered (MFMA-fragment-ordered) tile layout ----
// 64x64 bf16 tile = 8 chunks x 1024 B; chunk ch, lane l, bf16 j:
//   K^T tile: s = (ch>>1)*16 + (l&15), c = (ch&1)*32 + (l>>4)*8 + j
//   V  tile:  c = (ch>>1)*16 + (l&15), s = (ch&1)*32 + (l>>4)*8 + j
// -> a fragment ds_read_b128 / global b128 is base + lane*16: contiguous,
//    conflict-free, and matches global_load_lds's linear dest.
static constexpr int kTileEl = 4096;                       // 8192 B per tile
static constexpr size_t kTensorEl    = (size_t)128 * 16 * kTileEl;
static constexpr size_t kTensorBytes = kTensorEl * 2;      // 16 MiB per tensor

// legacy constant for fallback kernel
static constexpr int kLS = 72;

__device__ inline void async16(const void* g, void* l) {
  __builtin_amdgcn_global_load_lds(
      (const __attribute__((address_space(1))) void*)g,
      (__attribute__((address_space(3))) void*)l, 16, 0, 0);
}

// ---------------- Prepass: K (mask-folded, transposed) + V, chunk-ordered bf16 ----------------
__global__ __launch_bounds__(256, 8)
void prepass(const float* __restrict__ qkv, const float* __restrict__ mask,
             __bf16* __restrict__ kh, __bf16* __restrict__ vh)
{
  __shared__ float ts[64 * 65];
  const int tid = threadIdx.x;
  const int bid = blockIdx.x, bh = bid >> 4, tile = bid & 15;
  const int b = bh >> 4, h = bh & 15, t0 = tile * 64;
  const float* __restrict__ kb = qkv + (size_t)(b * 3072 + 1024 + h * 64) * kT;
  const float* __restrict__ vb = qkv + (size_t)(b * 3072 + 2048 + h * 64) * kT;
  const float* __restrict__ mrow = mask + (size_t)(h & 7) * kT;  // mask.repeat(n_heads,1)
  const size_t tbase = ((size_t)bh * 16 + tile) * kTileEl;

  // stage K*mask rows into LDS (row c, col s), coalesced f32x4 loads
  const int t4   = (tid & 15) * 4;
  const int crow = tid >> 4;
  const f32x4 m4 = *(const f32x4*)&mrow[t0 + t4];
  #pragma unroll
  for (int i = 0; i < 4; ++i) {
    const int c = i * 16 + crow;
    f32x4 k4 = *(const f32x4*)&kb[(size_t)c * kT + t0 + t4];
    k4 *= m4;                               // fold mask into K (s-axis only dependence)
    *(f32x4*)&ts[c * 65 + t4] = k4;
  }
  __syncthreads();

  // emit 2 pieces/thread: piece p -> chunk p>>6, lane p&63 (writes lane-contiguous)
  #pragma unroll
  for (int i = 0; i < 2; ++i) {
    const int p = i * 256 + tid;
    const int chunk = p >> 6, pl = p & 63;
    // V piece: direct global (16 rows x 128 B contiguous per wave) — issue loads first
    const int vc  = (chunk >> 1) * 16 + (pl & 15);
    const int vs0 = (chunk & 1) * 32 + (pl >> 4) * 8;
    const f32x4 va  = *(const f32x4*)&vb[(size_t)vc * kT + t0 + vs0];
    const f32x4 vbq = *(const f32x4*)&vb[(size_t)vc * kT + t0 + vs0 + 4];
    // K piece from LDS transpose (2-way max bank alias: free for b32)
    const int ks  = (chunk >> 1) * 16 + (pl & 15);
    const int kc0 = (chunk & 1) * 32 + (pl >> 4) * 8;
    bf16x8 k8, v8;
    #pragma unroll
    for (int j = 0; j < 8; ++j) k8[j] = (__bf16)ts[(kc0 + j) * 65 + ks];
    #pragma unroll
    for (int j = 0; j < 4; ++j) { v8[j] = (__bf16)va[j]; v8[4 + j] = (__bf16)vbq[j]; }
    *(bf16x8*)&kh[tbase + (size_t)p * 8] = k8;
    *(bf16x8*)&vh[tbase + (size_t)p * 8] = v8;
  }
}

// ---------------- Main: flash attention, 128-col blocks, 2-tile body ----------------
// == ROUND-3 STRUCTURE (best measured: 68.4 us) + V-before-stage issue order ==
// grid 1024 = 128 bh (low bits -> all 8 t-blocks of one head preserve bid%8 ->
// same XCD -> K/V L2-resident) x 8 t-pairs.
// Per barrier period: TWO K/V tiles; 8 barriers total. Dual interleaved QK
// chains (a0,a1) + dual sP buffers (round-3's proven ILP structure).
// KEY FIX vs round 3: gfx9 vmcnt completion is IN-ORDER, so a wait for a V
// fragment also drains every OLDER outstanding load. Round 3 issued the K
// stage loads BEFORE the V loads -> the compiler's V-wait at PV drained the
// K prefetch almost immediately (flight ~= QK phase only). Issuing u0's V
// loads FIRST makes the stage loads the NEWEST -> V-waits leave them in
// flight until u1's V consumption (~3/4 of the body of real flight time).
// Also: K pair-0 DMA issues BEFORE the Q prologue (ts relocated to
// smem+32512, overlapping only sK buf1 which is untouched until p=0's
// stage), removing the cold-start drain at the first barrier.
__global__ __launch_bounds__(256, 3)
void attn_main(const float* __restrict__ qkv,
               const __bf16* __restrict__ kh, const __bf16* __restrict__ vh,
               float* __restrict__ out)
{
  // [0,32768) sK ping-pong 2 x 16 KB (one K-tile PAIR each)
  // [32768,49152) sP: 4 waves x (2 halves x 2048)
  // prologue overlays float ts[64*65] = 16640 B on [32512,49152)
  __shared__ __align__(16) char smem[49152];

  const int tid  = threadIdx.x;
  const int lane = tid & 63;
  const int wave = tid >> 6;
  const int quad = lane >> 4;
  const int l15  = lane & 15;

  const int bid = blockIdx.x;
  const int bh  = bid & 127;
  const int tp  = bid >> 7;
  const int b   = bh >> 4;
  const int h   = bh & 15;
  const int t0  = tp * 128;
  const size_t hbase = (size_t)bh * 16;

  // ---- DMA K pair 0 (tiles 0,1 = 16 KB) into buffer 0 BEFORE the prologue:
  // the Q staging work below is its flight time ----
  {
    const char* g = (const char*)(kh + hbase * kTileEl) + (size_t)lane * 16;
    for (int i = wave; i < 16; i += 4) async16(g + i * 1024, smem + i * 1024);
  }

  // ---- prologue: Q fp32 -> LDS transpose -> hi/lo register frags (both halves) ----
  bf16x8 qh[2][2], ql[2][2];   // [half][kc]
  {
    float* ts = (float*)(smem + 32512);   // does NOT touch sK buf0 [0,16384)
    const float* __restrict__ qb = qkv + (size_t)(b * 3072 + h * 64) * kT;
    const int t4   = (tid & 15) * 4;
    const int crow = tid >> 4;
    const int trow = wave * 16 + l15;
    #pragma unroll
    for (int half = 0; half < 2; ++half) {
      const int tq0 = t0 + half * 64;
      #pragma unroll
      for (int i = 0; i < 4; ++i) {
        const int c = i * 16 + crow;
        f32x4 q4 = *(const f32x4*)&qb[(size_t)c * kT + tq0 + t4];
        q4 *= 0.18033688f;                 // 0.125 * log2(e)
        *(f32x4*)&ts[c * 65 + t4] = q4;
      }
      __syncthreads();
      #pragma unroll
      for (int kc = 0; kc < 2; ++kc) {
        bf16x8 hf, lf;
        #pragma unroll
        for (int j = 0; j < 8; ++j) {
          float q = ts[(kc * 32 + quad * 8 + j) * 65 + trow];  // 2-way alias: free
          __bf16 hi = (__bf16)q;
          hf[j] = hi;
          lf[j] = (__bf16)(q - (float)hi);
        }
        qh[half][kc] = hf;
        ql[half][kc] = lf;
      }
      __syncthreads();   // ts free for next half / sP use below
    }
  }

  f32x4 O0[4], O1[4];
  #pragma unroll
  for (int cc = 0; cc < 4; ++cc) {
    O0[cc] = (f32x4){0.f, 0.f, 0.f, 0.f};
    O1[cc] = (f32x4){0.f, 0.f, 0.f, 0.f};
  }
  f32x4 la0 = (f32x4){0.f, 0.f, 0.f, 0.f};   // vectorized denominators: 4 indep chains
  f32x4 la1 = (f32x4){0.f, 0.f, 0.f, 0.f};

  char* sP0 = smem + 32768 + wave * 4096;   // half-0 P buffer (2 KB)
  char* sP1 = sP0 + 2048;                   // half-1 P buffer (2 KB)
  // write addr for (sc): (sc>>1)<<10 | (sc&1)<<9 | pwr   (derived so the 64-lane
  // b64 write covers one contiguous 512 B region; read back is contiguous b128)
  const int pwr = (l15 << 4) + ((quad & 1) << 3) + ((quad >> 1) << 8);

  for (int p = 0; p < 8; ++p) {
    __syncthreads();   // K pair p drained (all waves); other buffer free

    const __bf16* __restrict__ vt0 = vh + (hbase + 2 * p) * kTileEl;
    const __bf16* __restrict__ vt1 = vt0 + kTileEl;

    // ---- u0 V frags issued FIRST (older than stage loads): the compiler's
    // V-wait before PV then leaves the stage loads in flight ----
    bf16x8 vA0[4], vA1[4];
    #pragma unroll
    for (int cc = 0; cc < 4; ++cc)
      vA0[cc] = *(const bf16x8*)&vt0[(size_t)(cc * 2) * 512 + lane * 8];
    #pragma unroll
    for (int cc = 0; cc < 4; ++cc)
      vA1[cc] = *(const bf16x8*)&vt0[(size_t)(cc * 2 + 1) * 512 + lane * 8];

    // ---- prefetch K pair p+1 (16 chunks distributed); newest VMEM ops ->
    // stay in flight until u1's V consumption ----
    if (p < 7) {
      const char* g = (const char*)(kh + (hbase + 2 * (p + 1)) * kTileEl) + (size_t)lane * 16;
      char* l = smem + ((p + 1) & 1) * 16384;
      for (int i = wave; i < 16; i += 4) async16(g + i * 1024, l + i * 1024);
    }

    // ================= u = 0 =================
    {
      const __bf16* __restrict__ sKt = (const __bf16*)(smem + (p & 1) * 16384);

      #pragma unroll
      for (int sc = 0; sc < 4; ++sc) {
        bf16x8 k0 = *(const bf16x8*)&sKt[(size_t)(sc * 2) * 512 + lane * 8];
        bf16x8 k1 = *(const bf16x8*)&sKt[(size_t)(sc * 2 + 1) * 512 + lane * 8];
        f32x4 a0 = (f32x4){0.f, 0.f, 0.f, 0.f};
        f32x4 a1 = (f32x4){0.f, 0.f, 0.f, 0.f};
        a0 = MFMA16(k0, ql[0][0], a0);
        a1 = MFMA16(k0, ql[1][0], a1);
        a0 = MFMA16(k0, qh[0][0], a0);
        a1 = MFMA16(k0, qh[1][0], a1);
        a0 = MFMA16(k1, ql[0][1], a0);
        a1 = MFMA16(k1, ql[1][1], a1);
        a0 = MFMA16(k1, qh[0][1], a0);
        a1 = MFMA16(k1, qh[1][1], a1);
        f32x4 e0, e1;
        #pragma unroll
        for (int r = 0; r < 4; ++r) {
          e0[r] = EXP2(a0[r]);
          e1[r] = EXP2(a1[r]);
        }
        la0 += e0;                        // f32 denominator, 4 indep chains
        la1 += e1;
        bf16x4 p0, p1;
        #pragma unroll
        for (int r = 0; r < 4; ++r) {
          p0[r] = (__bf16)e0[r];
          p1[r] = (__bf16)e1[r];
        }
        const int po = ((sc >> 1) << 10) + ((sc & 1) << 9) + pwr;
        *(bf16x4*)(sP0 + po) = p0;
        *(bf16x4*)(sP1 + po) = p1;
      }

      // P frags: contiguous 1 KB b128 reads (in-wave DS ordering, no barrier)
      bf16x8 pb00 = *(const bf16x8*)(sP0 + lane * 16);
      bf16x8 pb01 = *(const bf16x8*)(sP0 + 1024 + lane * 16);
      bf16x8 pb10 = *(const bf16x8*)(sP1 + lane * 16);
      bf16x8 pb11 = *(const bf16x8*)(sP1 + 1024 + lane * 16);

      #pragma unroll
      for (int cc = 0; cc < 4; ++cc) {
        O0[cc] = MFMA16(vA0[cc], pb00, O0[cc]);
        O1[cc] = MFMA16(vA0[cc], pb10, O1[cc]);
        O0[cc] = MFMA16(vA1[cc], pb01, O0[cc]);
        O1[cc] = MFMA16(vA1[cc], pb11, O1[cc]);
      }
    }

    // ================= u = 1 =================
    {
      const __bf16* __restrict__ sKt = (const __bf16*)(smem + (p & 1) * 16384 + 8192);

      bf16x8 vB0[4], vB1[4];
      #pragma unroll
      for (int cc = 0; cc < 4; ++cc)
        vB0[cc] = *(const bf16x8*)&vt1[(size_t)(cc * 2) * 512 + lane * 8];

      #pragma unroll
      for (int sc = 0; sc < 4; ++sc) {
        bf16x8 k0 = *(const bf16x8*)&sKt[(size_t)(sc * 2) * 512 + lane * 8];
        bf16x8 k1 = *(const bf16x8*)&sKt[(size_t)(sc * 2 + 1) * 512 + lane * 8];
        f32x4 a0 = (f32x4){0.f, 0.f, 0.f, 0.f};
        f32x4 a1 = (f32x4){0.f, 0.f, 0.f, 0.f};
        a0 = MFMA16(k0, ql[0][0], a0);
        a1 = MFMA16(k0, ql[1][0], a1);
        a0 = MFMA16(k0, qh[0][0], a0);
        a1 = MFMA16(k0, qh[1][0], a1);
        a0 = MFMA16(k1, ql[0][1], a0);
        a1 = MFMA16(k1, ql[1][1], a1);
        a0 = MFMA16(k1, qh[0][1], a0);
        a1 = MFMA16(k1, qh[1][1], a1);
        f32x4 e0, e1;
        #pragma unroll
        for (int r = 0; r < 4; ++r) {
          e0[r] = EXP2(a0[r]);
          e1[r] = EXP2(a1[r]);
        }
        la0 += e0;
        la1 += e1;
        bf16x4 p0, p1;
        #pragma unroll
        for (int r = 0; r < 4; ++r) {
          p0[r] = (__bf16)e0[r];
          p1[r] = (__bf16)e1[r];
        }
        const int po = ((sc >> 1) << 10) + ((sc & 1) << 9) + pwr;
        *(bf16x4*)(sP0 + po) = p0;
        *(bf16x4*)(sP1 + po) = p1;
      }

      #pragma unroll
      for (int cc = 0; cc < 4; ++cc)
        vB1[cc] = *(const bf16x8*)&vt1[(size_t)(cc * 2 + 1) * 512 + lane * 8];

      bf16x8 pb00 = *(const bf16x8*)(sP0 + lane * 16);
      bf16x8 pb01 = *(const bf16x8*)(sP0 + 1024 + lane * 16);
      bf16x8 pb10 = *(const bf16x8*)(sP1 + lane * 16);
      bf16x8 pb11 = *(const bf16x8*)(sP1 + 1024 + lane * 16);

      #pragma unroll
      for (int cc = 0; cc < 4; ++cc) {
        O0[cc] = MFMA16(vB0[cc], pb00, O0[cc]);
        O1[cc] = MFMA16(vB0[cc], pb10, O1[cc]);
        O0[cc] = MFMA16(vB1[cc], pb01, O0[cc]);
        O1[cc] = MFMA16(vB1[cc], pb11, O1[cc]);
      }
    }
  }

  // ---- epilogue: reduce denominators (4 lanes of f32x4, then cross-quad), store ----
  float ls0 = la0[0] + la0[1] + la0[2] + la0[3];
  float ls1 = la1[0] + la1[1] + la1[2] + la1[3];
  ls0 += __shfl_xor(ls0, 16);
  ls0 += __shfl_xor(ls0, 32);
  ls1 += __shfl_xor(ls1, 16);
  ls1 += __shfl_xor(ls1, 32);
  const float inv0 = 1.0f / ls0;
  const float inv1 = 1.0f / ls1;

  const int tcol = t0 + wave * 16 + l15;
  float* __restrict__ obase = out + (size_t)b * (1024 * 1024) + (size_t)(h * 64) * kT;
  #pragma unroll
  for (int cc = 0; cc < 4; ++cc) {
    #pragma unroll
    for (int r = 0; r < 4; ++r) {
      const int c = cc * 16 + quad * 4 + r;
      obase[(size_t)c * kT + tcol]      = O0[cc][r] * inv0;
      obase[(size_t)c * kT + tcol + 64] = O1[cc][r] * inv1;
    }
  }
}

// ---------------- Fallback (round-2 passing kernel, used if ws too small) ----------------
__global__ __launch_bounds__(256, 2)
void attn_fused(const float* __restrict__ qkv, const float* __restrict__ mask,
                float* __restrict__ out)
{
  __shared__ __align__(16) __bf16 Ahi[64 * kLS];
  __shared__ __align__(16) __bf16 Alo[64 * kLS];
  __shared__ __align__(16) __bf16 Vhi[64 * kLS];
  __shared__ __align__(16) __bf16 Vlo[64 * kLS];
  __shared__ __align__(16) __bf16 Phi[64 * kLS];
  __shared__ __align__(16) __bf16 Plo[64 * kLS];
  __shared__ __align__(16) float  ms[64];

  const int tid  = threadIdx.x;
  const int lane = tid & 63;
  const int wave = tid >> 6;
  const int quad = lane >> 4;
  const int l15  = lane & 15;

  const int bid = blockIdx.x;
  const int bh  = bid >> 4;
  const int tb  = bid & 15;
  const int b   = bh >> 4;
  const int h   = bh & 15;
  const int t0  = tb * 64;

  const float* __restrict__ qbase = qkv + (size_t)(b * 3072 + h * 64) * kT;
  const float* __restrict__ kbase = qkv + (size_t)(b * 3072 + 1024 + h * 64) * kT;
  const float* __restrict__ vbase = qkv + (size_t)(b * 3072 + 2048 + h * 64) * kT;
  const float* __restrict__ mrow  = mask + (size_t)(h & 7) * kT;

  const int sl = tid & 63;
  const int cg = tid >> 6;

  #pragma unroll
  for (int i = 0; i < 16; ++i) {
    const int c = cg * 16 + i;
    float v  = qbase[(size_t)c * kT + t0 + sl] * 0.125f;
    __bf16 hi = (__bf16)v;
    Ahi[sl * kLS + c] = hi;
    Alo[sl * kLS + c] = (__bf16)(v - (float)hi);
  }
  __syncthreads();

  bf16x8 qh[2], ql[2];
  {
    const int row = (wave * 16 + l15) * kLS;
    #pragma unroll
    for (int kc = 0; kc < 2; ++kc) {
      qh[kc] = *(const bf16x8*)&Ahi[row + kc * 32 + quad * 8];
      ql[kc] = *(const bf16x8*)&Alo[row + kc * 32 + quad * 8];
    }
  }
  __syncthreads();

  f32x4 O[4];
  #pragma unroll
  for (int cc = 0; cc < 4; ++cc) O[cc] = (f32x4){0.f, 0.f, 0.f, 0.f};
  float m_run = -__builtin_inff();
  float l_run = 0.f;

  for (int s0 = 0; s0 < kT; s0 += 64) {
    #pragma unroll
    for (int i = 0; i < 16; ++i) {
      const int c = cg * 16 + i;
      float kv   = kbase[(size_t)c * kT + s0 + sl];
      __bf16 khi = (__bf16)kv;
      Ahi[sl * kLS + c] = khi;
      Alo[sl * kLS + c] = (__bf16)(kv - (float)khi);
      float vv   = vbase[(size_t)c * kT + s0 + sl];
      __bf16 vhi = (__bf16)vv;
      Vhi[c * kLS + sl] = vhi;
      Vlo[c * kLS + sl] = (__bf16)(vv - (float)vhi);
    }
    if (tid < 64) ms[tid] = mrow[s0 + tid];
    __syncthreads();

    f32x4 S[4];
    #pragma unroll
    for (int sc = 0; sc < 4; ++sc) {
      f32x4 acc = (f32x4){0.f, 0.f, 0.f, 0.f};
      #pragma unroll
      for (int kc = 0; kc < 2; ++kc) {
        const int off = (sc * 16 + l15) * kLS + kc * 32 + quad * 8;
        bf16x8 kh8 = *(const bf16x8*)&Ahi[off];
        bf16x8 kl8 = *(const bf16x8*)&Alo[off];
        acc = MFMA16(kh8, ql[kc], acc);
        acc = MFMA16(kl8, qh[kc], acc);
        acc = MFMA16(kh8, qh[kc], acc);
      }
      S[sc] = acc;
    }

    float x[16];
    float tmax = -__builtin_inff();
    #pragma unroll
    for (int sc = 0; sc < 4; ++sc) {
      f32x4 mv = *(const f32x4*)&ms[sc * 16 + quad * 4];
      #pragma unroll
      for (int r = 0; r < 4; ++r) {
        float xv = S[sc][r] * mv[r];
        x[sc * 4 + r] = xv;
        tmax = fmaxf(tmax, xv);
      }
    }
    tmax = fmaxf(tmax, __shfl_xor(tmax, 16));
    tmax = fmaxf(tmax, __shfl_xor(tmax, 32));
    const float mnew  = fmaxf(m_run, tmax);
    const float alpha = __expf(m_run - mnew);
    float tsum = 0.f;
    #pragma unroll
    for (int i = 0; i < 16; ++i) {
      float p = __expf(x[i] - mnew);
      x[i] = p;
      tsum += p;
    }
    tsum += __shfl_xor(tsum, 16);
    tsum += __shfl_xor(tsum, 32);
    l_run = l_run * alpha + tsum;
    m_run = mnew;
    #pragma unroll
    for (int cc = 0; cc < 4; ++cc) O[cc] = O[cc] * alpha;

    const int prow = (wave * 16 + l15) * kLS;
    #pragma unroll
    for (int sc = 0; sc < 4; ++sc) {
      bf16x4 ph, pl;
      #pragma unroll
      for (int r = 0; r < 4; ++r) {
        float p   = x[sc * 4 + r];
        __bf16 hi = (__bf16)p;
        ph[r] = hi;
        pl[r] = (__bf16)(p - (float)hi);
      }
      *(bf16x4*)&Phi[prow + sc * 16 + quad * 4] = ph;
      *(bf16x4*)&Plo[prow + sc * 16 + quad * 4] = pl;
    }
    __syncthreads();

    bf16x8 pbh[2], pbl[2];
    #pragma unroll
    for (int kc = 0; kc < 2; ++kc) {
      pbh[kc] = *(const bf16x8*)&Phi[prow + kc * 32 + quad * 8];
      pbl[kc] = *(const bf16x8*)&Plo[prow + kc * 32 + quad * 8];
    }
    #pragma unroll
    for (int cc = 0; cc < 4; ++cc) {
      #pragma unroll
      for (int kc = 0; kc < 2; ++kc) {
        const int off = (cc * 16 + l15) * kLS + kc * 32 + quad * 8;
        bf16x8 v8 = *(const bf16x8*)&Vhi[off];
        bf16x8 w8 = *(const bf16x8*)&Vlo[off];
        O[cc] = MFMA16(v8, pbl[kc], O[cc]);
        O[cc] = MFMA16(w8, pbh[kc], O[cc]);
        O[cc] = MFMA16(v8, pbh[kc], O[cc]);
      }
    }
    __syncthreads();
  }

  const float inv  = 1.0f / l_run;
  const int   tcol = t0 + wave * 16 + l15;
  float* __restrict__ obase = out + (size_t)b * (1024 * 1024) + (size_t)(h * 64) * kT;
  #pragma unroll
  for (int cc = 0; cc < 4; ++cc) {
    #pragma unroll
    for (int r = 0; r < 4; ++r) {
      const int c = cc * 16 + quad * 4 + r;
      obase[(size_t)c * kT + tcol] = O[cc][r] * inv;
    }
  }
}

extern "C" void kernel_launch(void* const* d_in, const int* in_sizes, int n_in,
                              void* d_out, int out_size, void* d_ws, size_t ws_size,
                              hipStream_t stream)
{
  const float* qkv  = (const float*)d_in[0];  // (8, 3072, 1024) fp32
  const float* mask = (const float*)d_in[1];  // (8, 1024) fp32
  float* out = (float*)d_out;                 // (8, 1024, 1024) fp32
  (void)in_sizes; (void)n_in; (void)out_size;

  if (ws_size >= 2 * kTensorBytes) {
    char* w = (char*)d_ws;
    __bf16* kh = (__bf16*)(w + 0 * kTensorBytes);
    __bf16* vh = (__bf16*)(w + 1 * kTensorBytes);
    prepass<<<dim3(2048), dim3(256), 0, stream>>>(qkv, mask, kh, vh);
    attn_main<<<dim3(1024), dim3(256), 0, stream>>>(qkv, kh, vh, out);
  } else {
    attn_fused<<<dim3(2048), dim3(256), 0, stream>>>(qkv, mask, out);
  }
}